// Round 8
// baseline (5411.874 us; speedup 1.0000x reference)
//
#include <hip/hip_runtime.h>

typedef _Float16 f16;
typedef _Float16 f16x4 __attribute__((ext_vector_type(4)));
typedef _Float16 f16x8 __attribute__((ext_vector_type(8)));
typedef float    f32x4 __attribute__((ext_vector_type(4)));

#define MFMA16(a,b,c) __builtin_amdgcn_mfma_f32_16x16x32_f16((a),(b),(c),0,0,0)

constexpr unsigned NB = 64, NS = 256, NC = 64, NH = 512, NT = 128;
constexpr unsigned HSLOT = NB * NH;                       // f16 elems per h snapshot

// ---- workspace layout (total ~2.70 MB) ----
constexpr unsigned OFF_WX   = 0;                          // x as f16 [64][256][64]  (2 MB)
constexpr unsigned OFF_WLIN = OFF_WX   + NB*NS*NC*2;      // lin_W as f16 [64][512]  (64 KB)
constexpr unsigned OFF_EH0  = OFF_WLIN + NC*NH*2;         // 4 h-rings, 2 slots each (512 KB)
constexpr unsigned OFF_EH1  = OFF_EH0  + 2*HSLOT*2;
constexpr unsigned OFF_DH0  = OFF_EH1  + 2*HSLOT*2;
constexpr unsigned OFF_DH1  = OFF_DH0  + 2*HSLOT*2;
constexpr unsigned OFF_BAR  = OFF_DH1  + 2*HSLOT*2;       // barrier ints (8 KB zeroed)

// h rings: BLOCKED layout, elem(batch b, unit u) at (u/4)*256 + b*4 + (u%4).
// Producer WG writes 64 batches x 8B = 512B contiguous, full lines, no
// cross-WG line sharing (R7: killed the partial-line RMW storm).

// ============================ prep kernel ============================
__global__ void prep_convert(const float* __restrict__ x,
                             const float* __restrict__ linw,
                             char* __restrict__ ws)
{
    unsigned rel = blockIdx.x * 256u + threadIdx.x;
    if (rel < 262144u) {
        float4 v = ((const float4*)x)[rel];
        f16x4 o; o[0]=(f16)v.x; o[1]=(f16)v.y; o[2]=(f16)v.z; o[3]=(f16)v.w;
        ((f16x4*)(ws + OFF_WX))[rel] = o;
    } else if ((rel -= 262144u) < 8192u) {
        float4 v = ((const float4*)linw)[rel];
        f16x4 o; o[0]=(f16)v.x; o[1]=(f16)v.y; o[2]=(f16)v.z; o[3]=(f16)v.w;
        ((f16x4*)(ws + OFF_WLIN))[rel] = o;
    } else if ((rel -= 8192u) < 32768u) {         // zero all 4 h rings (contiguous)
        f16x8 z = {};
        ((f16x8*)(ws + OFF_EH0))[rel] = z;
    } else if ((rel -= 32768u) < 512u) {          // zero barrier block (8 KB)
        int4 z; z.x = z.y = z.z = z.w = 0;
        ((int4*)(ws + OFF_BAR))[rel] = z;
    }
}

// ============================ device helpers ============================

__device__ __forceinline__ float sigm(float v)   { return 1.f / (1.f + __expf(-v)); }
__device__ __forceinline__ float tanh_f(float v) { return 2.f / (1.f + __expf(-2.f * v)) - 1.f; }

// Fine-grained device-coherent h accesses (RELAXED/AGENT = single write-through
// store / cache-bypass load at the coherence point; no bulk L2 maintenance).
__device__ __forceinline__ void h_store8(f16* p, f16x4 v)
{
    union { unsigned long long u; f16x4 h; } c; c.h = v;
    __hip_atomic_store((unsigned long long*)p, c.u, __ATOMIC_RELAXED, __HIP_MEMORY_SCOPE_AGENT);
}
__device__ __forceinline__ f16x4 h_load8(const f16* p)
{
    unsigned long long v = __hip_atomic_load((const unsigned long long*)p,
                                             __ATOMIC_RELAXED, __HIP_MEMORY_SCOPE_AGENT);
    union { unsigned long long u; f16x4 h; } c; c.u = v;
    return c.h;
}
// A[m][kr..kr+7] from a blocked ring slot (kr multiple of 8)
__device__ __forceinline__ f16x8 h_load_blk(const f16* slot, int kr, int m)
{
    const f16* p = slot + ((kr >> 2) << 8) + (m << 2);
    f16x4 a = h_load8(p);
    f16x4 b = h_load8(p + 256);
    f16x8 r;
    r[0]=a[0]; r[1]=a[1]; r[2]=a[2]; r[3]=a[3];
    r[4]=b[0]; r[5]=b[1]; r[6]=b[2]; r[7]=b[3];
    return r;
}

// Barrier v3: 32 groups x 8 WGs, monotonic counters, NO root / NO flags.
// Arrival: one relaxed fetch_add on the group counter. Wait: wave 0's lanes
// 0..31 load the 32 counters in one vmem instr and __ballot-check
// cnt >= 8*round. Chain = arrival RMW + direct observe (2 L3 hops) vs R7's
// 4 hops (group RMW -> root RMW -> flag store -> flag observe).
// Ordering stays structural: leading __syncthreads drains all h stores
// (write-through, ack'd at coherence point) before tid0's arrival issues;
// consumer h loads bypass L2 and read the coherence point directly.
__device__ __forceinline__ void grid_barrier(int* bar, int wg, int tid, int& bgen)
{
    __syncthreads();                           // all waves done; stores drained
    const int target = bgen + 1;
    if (tid < 64) {
        if (tid == 0) {
            int* grp = bar + ((wg & 31) << 5); // 32 groups of 8, 128B apart
            __hip_atomic_fetch_add(grp, 1, __ATOMIC_RELAXED, __HIP_MEMORY_SCOPE_AGENT);
        }
        const int need = target << 3;          // 8 arrivals per group per round
        int* cptr = bar + ((tid & 31) << 5);
        for (;;) {
            int v = (tid < 32)
                ? __hip_atomic_load(cptr, __ATOMIC_RELAXED, __HIP_MEMORY_SCOPE_AGENT)
                : need;
            if (__ballot(v >= need) == ~0ull) break;
            __builtin_amdgcn_s_sleep(2);
        }
    }
    __syncthreads();
    bgen = target;
}

// load this WG's 16 weight rows ([A | B] concat along K) fp32 -> f16 LDS
__device__ __forceinline__ void load_wlds_f32(f16 (*Wlds)[1032],
                                              const float* __restrict__ A, int KA,
                                              const float* __restrict__ Bs, int KB,
                                              int u0, int tid)
{
    int nch = (KA + KB) >> 2;       // float4 chunks per row
    int tot = nch << 4;
    for (int idx = tid; idx < tot; idx += 256) {
        int j = idx / nch, ch = idx - j * nch;
        int k = ch << 2;
        int grow = ((j >> 2) << 9) + u0 + (j & 3);   // gate*512 + unit
        float4 v;
        if (k < KA) v = *(const float4*)(A + grow * KA + k);
        else        v = *(const float4*)(Bs + grow * KB + (k - KA));
        f16x4 o; o[0]=(f16)v.x; o[1]=(f16)v.y; o[2]=(f16)v.z; o[3]=(f16)v.w;
        *(f16x4*)&Wlds[j][k] = o;
    }
}

// decoder-L0 weights: rows = [Wfold = dec_Wih0 @ lin_W (512) | dec_Whh0 (512)]
__device__ __forceinline__ void load_wlds_fold(f16 (*Wlds)[1032],
                                               const float* __restrict__ dwih0,
                                               const float* __restrict__ linw,
                                               const float* __restrict__ dwhh0,
                                               int u0, int tid)
{
    {   // fold part: each thread computes 32 consecutive k in one row
        int idx = tid << 5;
        int j = idx >> 9, k0 = idx & 511;
        int grow = ((j >> 2) << 9) + u0 + (j & 3);
        float acc[32];
        #pragma unroll
        for (int q = 0; q < 32; ++q) acc[q] = 0.f;
        for (int c = 0; c < 64; ++c) {
            float wc = dwih0[grow * 64 + c];
            const float* lr = linw + c * 512 + k0;
            #pragma unroll
            for (int q = 0; q < 32; ++q) acc[q] += wc * lr[q];
        }
        #pragma unroll
        for (int q = 0; q < 32; ++q) Wlds[j][k0 + q] = (f16)acc[q];
    }
    int tot = 2048;                 // dwhh0 part: 16 rows x 128 float4
    for (int idx = tid; idx < tot; idx += 256) {
        int j = idx >> 7, ch = idx & 127, k = ch << 2;
        int grow = ((j >> 2) << 9) + u0 + (j & 3);
        float4 v = *(const float4*)(dwhh0 + grow * 512 + k);
        f16x4 o; o[0]=(f16)v.x; o[1]=(f16)v.y; o[2]=(f16)v.z; o[3]=(f16)v.w;
        *(f16x4*)&Wlds[j][512 + k] = o;
    }
}

// one recurrent step for this WG's 4 hidden units.
// NEW partition: each wave computes ALL K for ITS 16 batches (wave w ->
// batches 16w..16w+15). One accumulator per lane, no cross-wave reduction:
// Dp LDS round-trip + its __syncthreads are gone. Gate gather is 16 intra-
// wave shuffles (C layout: col=(g<<2)|uu, row=q*4+r => src lane =
// (lane&48)|(g<<2)|(lane&3), reg = (lane>>2)&3).
// Thread ownership (batch = 16*wv + (lane>>2), unit = u0 + (lane&3)) is fixed
// across ALL phases, so creg carries encoder->decoder untouched.
__device__ __forceinline__ void rnn_round(f16 (*Wlds)[1032],
                                          const f16* __restrict__ A0, int ld0, int K0,
                                          bool a0_plain,
                                          const f16* __restrict__ A1,
                                          int K, int kStart,
                                          const float* ba, float& creg,
                                          f16* __restrict__ ho,
                                          int u0, int tid)
{
    const int lane = tid & 63, wv = tid >> 6, q = lane >> 4, lo = lane & 15;
    const int wbase = wv << 4;                 // this wave's 16-batch tile
    const int nEnd = K >> 5;
    f32x4 ac = {0.f,0.f,0.f,0.f};
    #pragma unroll 2
    for (int s = kStart >> 5; s < nEnd; ++s) {
        int kk = (s << 5) + (q << 3);
        f16x8 bf = *(const f16x8*)&Wlds[lo][kk];
        f16x8 a;
        if (kk < K0) {                         // uniform per slice (K0 % 32 == 0)
            if (a0_plain) a = *(const f16x8*)(A0 + kk + (wbase + lo) * ld0);
            else          a = h_load_blk(A0, kk, wbase + lo);
        } else {
            a = h_load_blk(A1, kk - K0, wbase + lo);
        }
        ac = MFMA16(a, bf, ac);
    }
    // gather the 4 gate columns for this thread's (batch, unit)
    const int rsel  = (lane >> 2) & 3;
    const int sbase = (lane & 48) | (lane & 3);
    float v[4];
    #pragma unroll
    for (int g = 0; g < 4; ++g) {
        int src = sbase | (g << 2);
        float t0 = __shfl(ac[0], src);
        float t1 = __shfl(ac[1], src);
        float t2 = __shfl(ac[2], src);
        float t3 = __shfl(ac[3], src);
        float tv = (rsel == 0) ? t0 : (rsel == 1) ? t1 : (rsel == 2) ? t2 : t3;
        v[g] = tv + ba[g];
    }
    float ii = sigm(v[0]), ff = sigm(v[1]), gg = tanh_f(v[2]), oo = sigm(v[3]);
    creg = ff * creg + ii * gg;
    float h = oo * tanh_f(creg);
    // lanes 4k..4k+3 = same batch, units 0..3 -> pack into one 8B store
    float h1 = __shfl_down(h, 1);
    float h2 = __shfl_down(h, 2);
    float h3 = __shfl_down(h, 3);
    if ((lane & 3) == 0) {
        f16x4 hv; hv[0]=(f16)h; hv[1]=(f16)h1; hv[2]=(f16)h2; hv[3]=(f16)h3;
        int m = wbase + (lane >> 2);
        h_store8(ho + ((u0 >> 2) << 8) + (m << 2), hv);
    }
}

// out_t tile: 16 batches x 64 cols = h1_t @ lin_W^T + lin_b  (H1 blocked)
__device__ __forceinline__ void out_gemm(const f16* __restrict__ H1,
                                         const f16* __restrict__ LW,
                                         const float* __restrict__ linb,
                                         float* __restrict__ out,
                                         int w, int t, int tid)
{
    const int lane = tid & 63, wv = tid >> 6, q = lane >> 4, lo = lane & 15;
    int b0 = w << 4;
    f32x4 ac = {0.f,0.f,0.f,0.f};
    int c0 = wv << 4;
    #pragma unroll 4
    for (int s = 0; s < 16; ++s) {
        int kk = (s << 5) + (q << 3);
        f16x8 bf = *(const f16x8*)(LW + (c0 + lo) * 512 + kk);
        f16x8 a  = h_load_blk(H1, kk, b0 + lo);
        ac = MFMA16(a, bf, ac);
    }
    float lb = linb[c0 + lo];
    #pragma unroll
    for (int r = 0; r < 4; ++r) {
        int b = b0 + (q << 2) + r;
        out[(size_t)b * (NT * NC) + t * NC + c0 + lo] = ac[r] + lb;
    }
}

// ============================ main persistent kernel ============================
// Plain (non-cooperative) launch: 256 WGs x 256 thr, ~33 KB LDS/WG -> >=3
// WGs/CU capacity, whole grid co-resident by capacity; hand-rolled device
// barrier cannot deadlock. Cooperative launch is not graph-capture-safe.

__global__ void __launch_bounds__(256)
lstm_main(char* __restrict__ ws,
          const float* __restrict__ x,
          const float* __restrict__ wih0, const float* __restrict__ whh0, const float* __restrict__ eb0,
          const float* __restrict__ wih1, const float* __restrict__ whh1, const float* __restrict__ eb1,
          const float* __restrict__ dwih0, const float* __restrict__ dwhh0, const float* __restrict__ db0,
          const float* __restrict__ dwih1, const float* __restrict__ dwhh1, const float* __restrict__ db1,
          const float* __restrict__ linw, const float* __restrict__ linb,
          float* __restrict__ out)
{
    __shared__ f16 Wlds[16][1032];   // this WG's 16 weight rows (K-padded)

    const int wg = blockIdx.x, tid = threadIdx.x;
    const bool isL0 = wg < 128;
    const int u0 = (wg & 127) << 2;
    const int uu = tid & 3;
    int* bar = (int*)(ws + OFF_BAR);
    int bgen = 0;

    const f16* WX   = (const f16*)(ws + OFF_WX);
    const f16* WLIN = (const f16*)(ws + OFF_WLIN);
    f16* EH0 = (f16*)(ws + OFF_EH0);
    f16* EH1 = (f16*)(ws + OFF_EH1);
    f16* DH0 = (f16*)(ws + OFF_DH0);
    f16* DH1 = (f16*)(ws + OFF_DH1);

    // ---------------- encoder (layer1 pipelined one step behind layer0) ----------------
    if (isL0) load_wlds_f32(Wlds, wih0,  64, whh0, 512, u0, tid);
    else      load_wlds_f32(Wlds, wih1, 512, whh1, 512, u0, tid);
    __syncthreads();

    float ba[4];
    {
        const float* bs = isL0 ? eb0 : eb1;
        #pragma unroll
        for (int g = 0; g < 4; ++g) ba[g] = bs[(g << 9) + u0 + uu];
    }
    float creg = 0.f;   // cell state: fixed (batch,unit) per thread across ALL phases

    for (int r = 0; r <= (int)NS; ++r) {
        if (isL0 && r < (int)NS) {
            rnn_round(Wlds,
                      WX + r * 64, NS * NC, 64, true,
                      EH0 + ((r + 1) & 1) * HSLOT,
                      576, 0, ba, creg,
                      EH0 + (r & 1) * HSLOT, u0, tid);
        } else if (!isL0 && r >= 1) {
            int t = r - 1;
            rnn_round(Wlds,
                      EH0 + (t & 1) * HSLOT, 512, 512, false,
                      EH1 + ((t + 1) & 1) * HSLOT,
                      1024, 0, ba, creg,
                      EH1 + (t & 1) * HSLOT, u0, tid);
        }
        grid_barrier(bar, wg, tid, bgen);
    }

    // ---------------- decoder setup (fold linear into layer0) ----------------
    float baI[4];
    if (isL0) {
        load_wlds_fold(Wlds, dwih0, linw, dwhh0, u0, tid);
        const int m = ((tid >> 6) << 4) | ((tid & 63) >> 2);   // this thread's batch
        const float* xr = x + m * (NS * NC) + (NS - 1) * NC;
        #pragma unroll
        for (int g = 0; g < 4; ++g) {
            int row = (g << 9) + u0 + uu;
            const float* wr = dwih0 + row * 64;
            float bsum = 0.f, xsum = 0.f;
            for (int c = 0; c < 64; ++c) { bsum += linb[c] * wr[c]; xsum += xr[c] * wr[c]; }
            ba[g]  = db0[row] + bsum;   // folded bias (t>=1)
            baI[g] = db0[row] + xsum;   // t==0 bias: x_last @ dec_Wih0^T + dec_b0
        }
    } else {
        load_wlds_f32(Wlds, dwih1, 512, dwhh1, 512, u0, tid);
        #pragma unroll
        for (int g = 0; g < 4; ++g) { ba[g] = db1[(g << 9) + u0 + uu]; baI[g] = 0.f; }
    }
    __syncthreads();

    // ---------------- decoder: 2 rounds/step; idle WGs 128..131 emit out_{t-1} ----------------
    for (int d = 0; d < 2 * (int)NT; ++d) {
        int t = d >> 1;
        if ((d & 1) == 0) {
            if (isL0) {
                const f16* A0 = (t == 0) ? EH1 + HSLOT : DH1 + ((t + 1) & 1) * HSLOT; // h1_{t-1} (Wfold)
                const f16* A1 = (t == 0) ? EH0 + HSLOT : DH0 + ((t + 1) & 1) * HSLOT; // h0_{t-1} (Whh0)
                rnn_round(Wlds, A0, 512, 512, false, A1, 1024, (t == 0) ? 512 : 0,
                          (t == 0) ? baI : ba, creg,
                          DH0 + (t & 1) * HSLOT, u0, tid);
            } else if (wg < 132 && t >= 1) {
                out_gemm(DH1 + ((t - 1) & 1) * HSLOT, WLIN, linb, out, wg - 128, t - 1, tid);
            }
        } else {
            if (!isL0) {
                const f16* A0 = DH0 + (t & 1) * HSLOT;                                 // h0_t (Wih1)
                const f16* A1 = (t == 0) ? EH1 + HSLOT : DH1 + ((t + 1) & 1) * HSLOT;  // h1_{t-1} (Whh1)
                rnn_round(Wlds, A0, 512, 512, false, A1, 1024, 0, ba, creg,
                          DH1 + (t & 1) * HSLOT, u0, tid);
            }
        }
        grid_barrier(bar, wg, tid, bgen);
    }

    // final out_{127} (h1_{127} is in DH1 slot 1; last grid_barrier already synced it)
    if (!isL0 && wg < 132)
        out_gemm(DH1 + HSLOT, WLIN, linb, out, wg - 128, (int)NT - 1, tid);
}

// ============================ host launch ============================

extern "C" void kernel_launch(void* const* d_in, const int* in_sizes, int n_in,
                              void* d_out, int out_size, void* d_ws, size_t ws_size,
                              hipStream_t stream)
{
    // setup_inputs() dict order: x, target_len, enc_Wih0, enc_Whh0, enc_b0,
    // enc_Wih1, enc_Whh1, enc_b1, dec_Wih0, dec_Whh0, dec_b0, dec_Wih1,
    // dec_Whh1, dec_b1, lin_W, lin_b.  (target_len at index 1!)
    const float* x     = (const float*)d_in[0];
    const float* wih0  = (const float*)d_in[2];
    const float* whh0  = (const float*)d_in[3];
    const float* eb0   = (const float*)d_in[4];
    const float* wih1  = (const float*)d_in[5];
    const float* whh1  = (const float*)d_in[6];
    const float* eb1   = (const float*)d_in[7];
    const float* dwih0 = (const float*)d_in[8];
    const float* dwhh0 = (const float*)d_in[9];
    const float* db0   = (const float*)d_in[10];
    const float* dwih1 = (const float*)d_in[11];
    const float* dwhh1 = (const float*)d_in[12];
    const float* db1   = (const float*)d_in[13];
    const float* linw  = (const float*)d_in[14];
    const float* linb  = (const float*)d_in[15];
    char* ws    = (char*)d_ws;
    float* outp = (float*)d_out;

    prep_convert<<<1187, 256, 0, stream>>>(x, linw, ws);

    // plain launch (graph-capture safe); co-residency by capacity, see comment above
    lstm_main<<<256, 256, 0, stream>>>(ws, x, wih0, whh0, eb0, wih1, whh1, eb1,
                                       dwih0, dwhh0, db0, dwih1, dwhh1, db1,
                                       linw, linb, outp);
}

// Round 9
// 5198.924 us; speedup vs baseline: 1.0410x; 1.0410x over previous
//
#include <hip/hip_runtime.h>

typedef _Float16 f16;
typedef _Float16 f16x4 __attribute__((ext_vector_type(4)));
typedef _Float16 f16x8 __attribute__((ext_vector_type(8)));
typedef float    f32x4 __attribute__((ext_vector_type(4)));

#define MFMA16(a,b,c) __builtin_amdgcn_mfma_f32_16x16x32_f16((a),(b),(c),0,0,0)

constexpr unsigned NB = 64, NS = 256, NC = 64, NH = 512, NT = 128;
constexpr unsigned HSLOT = NB * NH;                       // f16 elems per h snapshot

// ---- workspace layout (total ~2.70 MB) ----
constexpr unsigned OFF_WX   = 0;                          // x as f16 [64][256][64]  (2 MB)
constexpr unsigned OFF_WLIN = OFF_WX   + NB*NS*NC*2;      // lin_W as f16 [64][512]  (64 KB)
constexpr unsigned OFF_EH0  = OFF_WLIN + NC*NH*2;         // 4 h-rings, 2 slots each (512 KB)
constexpr unsigned OFF_EH1  = OFF_EH0  + 2*HSLOT*2;
constexpr unsigned OFF_DH0  = OFF_EH1  + 2*HSLOT*2;
constexpr unsigned OFF_DH1  = OFF_DH0  + 2*HSLOT*2;
constexpr unsigned OFF_BAR  = OFF_DH1  + 2*HSLOT*2;       // barrier ints (8 KB zeroed)

// h rings: BLOCKED layout, elem(batch b, unit u) at (u/4)*256 + b*4 + (u%4).
// Producer WG writes 64 batches x 8B = 512B contiguous, full lines, no
// cross-WG line sharing (R7: killed the partial-line RMW storm).

// ============================ prep kernel ============================
__global__ void prep_convert(const float* __restrict__ x,
                             const float* __restrict__ linw,
                             char* __restrict__ ws)
{
    unsigned rel = blockIdx.x * 256u + threadIdx.x;
    if (rel < 262144u) {
        float4 v = ((const float4*)x)[rel];
        f16x4 o; o[0]=(f16)v.x; o[1]=(f16)v.y; o[2]=(f16)v.z; o[3]=(f16)v.w;
        ((f16x4*)(ws + OFF_WX))[rel] = o;
    } else if ((rel -= 262144u) < 8192u) {
        float4 v = ((const float4*)linw)[rel];
        f16x4 o; o[0]=(f16)v.x; o[1]=(f16)v.y; o[2]=(f16)v.z; o[3]=(f16)v.w;
        ((f16x4*)(ws + OFF_WLIN))[rel] = o;
    } else if ((rel -= 8192u) < 32768u) {         // zero all 4 h rings (contiguous)
        f16x8 z = {};
        ((f16x8*)(ws + OFF_EH0))[rel] = z;
    } else if ((rel -= 32768u) < 512u) {          // zero barrier block (8 KB)
        int4 z; z.x = z.y = z.z = z.w = 0;
        ((int4*)(ws + OFF_BAR))[rel] = z;
    }
}

// ============================ device helpers ============================

__device__ __forceinline__ float sigm(float v)   { return 1.f / (1.f + __expf(-v)); }
__device__ __forceinline__ float tanh_f(float v) { return 2.f / (1.f + __expf(-2.f * v)) - 1.f; }

// Fine-grained device-coherent h accesses (RELAXED/AGENT = single write-through
// store / cache-bypass load at the coherence point; no bulk L2 maintenance).
__device__ __forceinline__ void h_store8(f16* p, f16x4 v)
{
    union { unsigned long long u; f16x4 h; } c; c.h = v;
    __hip_atomic_store((unsigned long long*)p, c.u, __ATOMIC_RELAXED, __HIP_MEMORY_SCOPE_AGENT);
}
__device__ __forceinline__ f16x4 h_load8(const f16* p)
{
    unsigned long long v = __hip_atomic_load((const unsigned long long*)p,
                                             __ATOMIC_RELAXED, __HIP_MEMORY_SCOPE_AGENT);
    union { unsigned long long u; f16x4 h; } c; c.u = v;
    return c.h;
}
// A[m][kr..kr+7] from a blocked ring slot (kr multiple of 8)
__device__ __forceinline__ f16x8 h_load_blk(const f16* slot, int kr, int m)
{
    const f16* p = slot + ((kr >> 2) << 8) + (m << 2);
    f16x4 a = h_load8(p);
    f16x4 b = h_load8(p + 256);
    f16x8 r;
    r[0]=a[0]; r[1]=a[1]; r[2]=a[2]; r[3]=a[3];
    r[4]=b[0]; r[5]=b[1]; r[6]=b[2]; r[7]=b[3];
    return r;
}

// Barrier: R7-proven topology (16 groups x 16 WGs, root counter, 16
// distributed release-flag lines; 16 pollers per flag line). ALL RELAXED.
// R8's v3 (all 256 WGs polling 32 counter lines = 8192 in-flight line reads,
// contending with the arrival RMWs) REGRESSED 2.86->5.41ms; reverted.
// Ordering is structural: leading __syncthreads drains all h stores
// (write-through, ack'd at coherence point) before tid0's arrival issues;
// consumer h loads bypass L2 and read the coherence point directly.
__device__ __forceinline__ void grid_barrier(int* bar, int wg, int tid, int& bgen)
{
    __syncthreads();                           // drain all threads' stores/loads
    if (tid == 0) {
        const int g = wg >> 4;                 // 16 groups of 16 WGs
        int* grp   = bar + g * 32;             // 128B-spaced counters
        int* root  = bar + 16 * 32;
        int* flags = bar + 17 * 32;            // 16 flag words, 128B apart
        const int target = bgen + 1;

        int old = __hip_atomic_fetch_add(grp, 1, __ATOMIC_RELAXED, __HIP_MEMORY_SCOPE_AGENT);
        if ((old & 15) == 15) {                // group complete
            int ro = __hip_atomic_fetch_add(root, 1, __ATOMIC_RELAXED, __HIP_MEMORY_SCOPE_AGENT);
            if ((ro & 15) == 15) {             // all 16 groups complete
                #pragma unroll
                for (int i = 0; i < 16; ++i)
                    __hip_atomic_store(flags + i * 32, target, __ATOMIC_RELAXED, __HIP_MEMORY_SCOPE_AGENT);
            }
        }
        int* myf = flags + g * 32;
        while (__hip_atomic_load(myf, __ATOMIC_RELAXED, __HIP_MEMORY_SCOPE_AGENT) < target)
            __builtin_amdgcn_s_sleep(1);
        bgen = target;
    }
    __syncthreads();
}

// load this WG's 16 weight rows ([A | B] concat along K) fp32 -> f16 LDS
__device__ __forceinline__ void load_wlds_f32(f16 (*Wlds)[1032],
                                              const float* __restrict__ A, int KA,
                                              const float* __restrict__ Bs, int KB,
                                              int u0, int tid)
{
    int nch = (KA + KB) >> 2;       // float4 chunks per row
    int tot = nch << 4;
    for (int idx = tid; idx < tot; idx += 256) {
        int j = idx / nch, ch = idx - j * nch;
        int k = ch << 2;
        int grow = ((j >> 2) << 9) + u0 + (j & 3);   // gate*512 + unit
        float4 v;
        if (k < KA) v = *(const float4*)(A + grow * KA + k);
        else        v = *(const float4*)(Bs + grow * KB + (k - KA));
        f16x4 o; o[0]=(f16)v.x; o[1]=(f16)v.y; o[2]=(f16)v.z; o[3]=(f16)v.w;
        *(f16x4*)&Wlds[j][k] = o;
    }
}

// decoder-L0 weights: rows = [Wfold = dec_Wih0 @ lin_W (512) | dec_Whh0 (512)]
__device__ __forceinline__ void load_wlds_fold(f16 (*Wlds)[1032],
                                               const float* __restrict__ dwih0,
                                               const float* __restrict__ linw,
                                               const float* __restrict__ dwhh0,
                                               int u0, int tid)
{
    {   // fold part: each thread computes 32 consecutive k in one row
        int idx = tid << 5;
        int j = idx >> 9, k0 = idx & 511;
        int grow = ((j >> 2) << 9) + u0 + (j & 3);
        float acc[32];
        #pragma unroll
        for (int q = 0; q < 32; ++q) acc[q] = 0.f;
        for (int c = 0; c < 64; ++c) {
            float wc = dwih0[grow * 64 + c];
            const float* lr = linw + c * 512 + k0;
            #pragma unroll
            for (int q = 0; q < 32; ++q) acc[q] += wc * lr[q];
        }
        #pragma unroll
        for (int q = 0; q < 32; ++q) Wlds[j][k0 + q] = (f16)acc[q];
    }
    int tot = 2048;                 // dwhh0 part: 16 rows x 128 float4
    for (int idx = tid; idx < tot; idx += 256) {
        int j = idx >> 7, ch = idx & 127, k = ch << 2;
        int grow = ((j >> 2) << 9) + u0 + (j & 3);
        float4 v = *(const float4*)(dwhh0 + grow * 512 + k);
        f16x4 o; o[0]=(f16)v.x; o[1]=(f16)v.y; o[2]=(f16)v.z; o[3]=(f16)v.w;
        *(f16x4*)&Wlds[j][512 + k] = o;
    }
}

// one recurrent step for this WG's 4 hidden units.
// Partition (kept from R8): each wave computes ALL K for ITS 16 batches.
// One accumulator per lane, no cross-wave reduction (no Dp LDS, no extra
// __syncthreads). Gate gather = intra-wave shuffles (C layout: col=(g<<2)|uu,
// row=q*4+r => src lane = (lane&48)|(g<<2)|(lane&3), reg = (lane>>2)&3).
// Thread ownership (batch = 16*wv + (lane>>2), unit = u0 + (lane&3)) is fixed
// across ALL phases, so creg carries encoder->decoder untouched.
__device__ __forceinline__ void rnn_round(f16 (*Wlds)[1032],
                                          const f16* __restrict__ A0, int ld0, int K0,
                                          bool a0_plain,
                                          const f16* __restrict__ A1,
                                          int K, int kStart,
                                          const float* ba, float& creg,
                                          f16* __restrict__ ho,
                                          int u0, int tid)
{
    const int lane = tid & 63, wv = tid >> 6, q = lane >> 4, lo = lane & 15;
    const int wbase = wv << 4;                 // this wave's 16-batch tile
    const int nEnd = K >> 5;
    f32x4 ac = {0.f,0.f,0.f,0.f};
    #pragma unroll 2
    for (int s = kStart >> 5; s < nEnd; ++s) {
        int kk = (s << 5) + (q << 3);
        f16x8 bf = *(const f16x8*)&Wlds[lo][kk];
        f16x8 a;
        if (kk < K0) {                         // uniform per slice (K0 % 32 == 0)
            if (a0_plain) a = *(const f16x8*)(A0 + kk + (wbase + lo) * ld0);
            else          a = h_load_blk(A0, kk, wbase + lo);
        } else {
            a = h_load_blk(A1, kk - K0, wbase + lo);
        }
        ac = MFMA16(a, bf, ac);
    }
    // gather the 4 gate columns for this thread's (batch, unit)
    const int rsel  = (lane >> 2) & 3;
    const int sbase = (lane & 48) | (lane & 3);
    float v[4];
    #pragma unroll
    for (int g = 0; g < 4; ++g) {
        int src = sbase | (g << 2);
        float t0 = __shfl(ac[0], src);
        float t1 = __shfl(ac[1], src);
        float t2 = __shfl(ac[2], src);
        float t3 = __shfl(ac[3], src);
        float tv = (rsel == 0) ? t0 : (rsel == 1) ? t1 : (rsel == 2) ? t2 : t3;
        v[g] = tv + ba[g];
    }
    float ii = sigm(v[0]), ff = sigm(v[1]), gg = tanh_f(v[2]), oo = sigm(v[3]);
    creg = ff * creg + ii * gg;
    float h = oo * tanh_f(creg);
    // lanes 4k..4k+3 = same batch, units 0..3 -> pack into one 8B store
    float h1 = __shfl_down(h, 1);
    float h2 = __shfl_down(h, 2);
    float h3 = __shfl_down(h, 3);
    if ((lane & 3) == 0) {
        f16x4 hv; hv[0]=(f16)h; hv[1]=(f16)h1; hv[2]=(f16)h2; hv[3]=(f16)h3;
        int m = wbase + (lane >> 2);
        h_store8(ho + ((u0 >> 2) << 8) + (m << 2), hv);
    }
}

// out_t tile: 16 batches x 64 cols = h1_t @ lin_W^T + lin_b  (H1 blocked)
__device__ __forceinline__ void out_gemm(const f16* __restrict__ H1,
                                         const f16* __restrict__ LW,
                                         const float* __restrict__ linb,
                                         float* __restrict__ out,
                                         int w, int t, int tid)
{
    const int lane = tid & 63, wv = tid >> 6, q = lane >> 4, lo = lane & 15;
    int b0 = w << 4;
    f32x4 ac = {0.f,0.f,0.f,0.f};
    int c0 = wv << 4;
    #pragma unroll 4
    for (int s = 0; s < 16; ++s) {
        int kk = (s << 5) + (q << 3);
        f16x8 bf = *(const f16x8*)(LW + (c0 + lo) * 512 + kk);
        f16x8 a  = h_load_blk(H1, kk, b0 + lo);
        ac = MFMA16(a, bf, ac);
    }
    float lb = linb[c0 + lo];
    #pragma unroll
    for (int r = 0; r < 4; ++r) {
        int b = b0 + (q << 2) + r;
        out[(size_t)b * (NT * NC) + t * NC + c0 + lo] = ac[r] + lb;
    }
}

// ============================ main persistent kernel ============================
// Plain (non-cooperative) launch: 256 WGs x 256 thr, ~33 KB LDS/WG -> >=3
// WGs/CU capacity, whole grid co-resident by capacity; hand-rolled device
// barrier cannot deadlock. Cooperative launch is not graph-capture-safe.

__global__ void __launch_bounds__(256)
lstm_main(char* __restrict__ ws,
          const float* __restrict__ x,
          const float* __restrict__ wih0, const float* __restrict__ whh0, const float* __restrict__ eb0,
          const float* __restrict__ wih1, const float* __restrict__ whh1, const float* __restrict__ eb1,
          const float* __restrict__ dwih0, const float* __restrict__ dwhh0, const float* __restrict__ db0,
          const float* __restrict__ dwih1, const float* __restrict__ dwhh1, const float* __restrict__ db1,
          const float* __restrict__ linw, const float* __restrict__ linb,
          float* __restrict__ out)
{
    __shared__ f16 Wlds[16][1032];   // this WG's 16 weight rows (K-padded)

    const int wg = blockIdx.x, tid = threadIdx.x;
    const bool isL0 = wg < 128;
    const int u0 = (wg & 127) << 2;
    const int uu = tid & 3;
    int* bar = (int*)(ws + OFF_BAR);
    int bgen = 0;

    const f16* WX   = (const f16*)(ws + OFF_WX);
    const f16* WLIN = (const f16*)(ws + OFF_WLIN);
    f16* EH0 = (f16*)(ws + OFF_EH0);
    f16* EH1 = (f16*)(ws + OFF_EH1);
    f16* DH0 = (f16*)(ws + OFF_DH0);
    f16* DH1 = (f16*)(ws + OFF_DH1);

    // ---------------- encoder (layer1 pipelined one step behind layer0) ----------------
    if (isL0) load_wlds_f32(Wlds, wih0,  64, whh0, 512, u0, tid);
    else      load_wlds_f32(Wlds, wih1, 512, whh1, 512, u0, tid);
    __syncthreads();

    float ba[4];
    {
        const float* bs = isL0 ? eb0 : eb1;
        #pragma unroll
        for (int g = 0; g < 4; ++g) ba[g] = bs[(g << 9) + u0 + uu];
    }
    float creg = 0.f;   // cell state: fixed (batch,unit) per thread across ALL phases

    for (int r = 0; r <= (int)NS; ++r) {
        if (isL0 && r < (int)NS) {
            rnn_round(Wlds,
                      WX + r * 64, NS * NC, 64, true,
                      EH0 + ((r + 1) & 1) * HSLOT,
                      576, 0, ba, creg,
                      EH0 + (r & 1) * HSLOT, u0, tid);
        } else if (!isL0 && r >= 1) {
            int t = r - 1;
            rnn_round(Wlds,
                      EH0 + (t & 1) * HSLOT, 512, 512, false,
                      EH1 + ((t + 1) & 1) * HSLOT,
                      1024, 0, ba, creg,
                      EH1 + (t & 1) * HSLOT, u0, tid);
        }
        grid_barrier(bar, wg, tid, bgen);
    }

    // ---------------- decoder setup (fold linear into layer0) ----------------
    float baI[4];
    if (isL0) {
        load_wlds_fold(Wlds, dwih0, linw, dwhh0, u0, tid);
        const int m = ((tid >> 6) << 4) | ((tid & 63) >> 2);   // this thread's batch
        const float* xr = x + m * (NS * NC) + (NS - 1) * NC;
        #pragma unroll
        for (int g = 0; g < 4; ++g) {
            int row = (g << 9) + u0 + uu;
            const float* wr = dwih0 + row * 64;
            float bsum = 0.f, xsum = 0.f;
            for (int c = 0; c < 64; ++c) { bsum += linb[c] * wr[c]; xsum += xr[c] * wr[c]; }
            ba[g]  = db0[row] + bsum;   // folded bias (t>=1)
            baI[g] = db0[row] + xsum;   // t==0 bias: x_last @ dec_Wih0^T + dec_b0
        }
    } else {
        load_wlds_f32(Wlds, dwih1, 512, dwhh1, 512, u0, tid);
        #pragma unroll
        for (int g = 0; g < 4; ++g) { ba[g] = db1[(g << 9) + u0 + uu]; baI[g] = 0.f; }
    }
    __syncthreads();

    // ---------------- decoder: 2 rounds/step; idle WGs 128..131 emit out_{t-1} ----------------
    for (int d = 0; d < 2 * (int)NT; ++d) {
        int t = d >> 1;
        if ((d & 1) == 0) {
            if (isL0) {
                const f16* A0 = (t == 0) ? EH1 + HSLOT : DH1 + ((t + 1) & 1) * HSLOT; // h1_{t-1} (Wfold)
                const f16* A1 = (t == 0) ? EH0 + HSLOT : DH0 + ((t + 1) & 1) * HSLOT; // h0_{t-1} (Whh0)
                rnn_round(Wlds, A0, 512, 512, false, A1, 1024, (t == 0) ? 512 : 0,
                          (t == 0) ? baI : ba, creg,
                          DH0 + (t & 1) * HSLOT, u0, tid);
            } else if (wg < 132 && t >= 1) {
                out_gemm(DH1 + ((t - 1) & 1) * HSLOT, WLIN, linb, out, wg - 128, t - 1, tid);
            }
        } else {
            if (!isL0) {
                const f16* A0 = DH0 + (t & 1) * HSLOT;                                 // h0_t (Wih1)
                const f16* A1 = (t == 0) ? EH1 + HSLOT : DH1 + ((t + 1) & 1) * HSLOT;  // h1_{t-1} (Whh1)
                rnn_round(Wlds, A0, 512, 512, false, A1, 1024, 0, ba, creg,
                          DH1 + (t & 1) * HSLOT, u0, tid);
            }
        }
        grid_barrier(bar, wg, tid, bgen);
    }

    // final out_{127} (h1_{127} is in DH1 slot 1; last grid_barrier already synced it)
    if (!isL0 && wg < 132)
        out_gemm(DH1 + HSLOT, WLIN, linb, out, wg - 128, (int)NT - 1, tid);
}

// ============================ host launch ============================

extern "C" void kernel_launch(void* const* d_in, const int* in_sizes, int n_in,
                              void* d_out, int out_size, void* d_ws, size_t ws_size,
                              hipStream_t stream)
{
    // setup_inputs() dict order: x, target_len, enc_Wih0, enc_Whh0, enc_b0,
    // enc_Wih1, enc_Whh1, enc_b1, dec_Wih0, dec_Whh0, dec_b0, dec_Wih1,
    // dec_Whh1, dec_b1, lin_W, lin_b.  (target_len at index 1!)
    const float* x     = (const float*)d_in[0];
    const float* wih0  = (const float*)d_in[2];
    const float* whh0  = (const float*)d_in[3];
    const float* eb0   = (const float*)d_in[4];
    const float* wih1  = (const float*)d_in[5];
    const float* whh1  = (const float*)d_in[6];
    const float* eb1   = (const float*)d_in[7];
    const float* dwih0 = (const float*)d_in[8];
    const float* dwhh0 = (const float*)d_in[9];
    const float* db0   = (const float*)d_in[10];
    const float* dwih1 = (const float*)d_in[11];
    const float* dwhh1 = (const float*)d_in[12];
    const float* db1   = (const float*)d_in[13];
    const float* linw  = (const float*)d_in[14];
    const float* linb  = (const float*)d_in[15];
    char* ws    = (char*)d_ws;
    float* outp = (float*)d_out;

    prep_convert<<<1187, 256, 0, stream>>>(x, linw, ws);

    // plain launch (graph-capture safe); co-residency by capacity, see comment above
    lstm_main<<<256, 256, 0, stream>>>(ws, x, wih0, whh0, eb0, wih1, whh1, eb1,
                                       dwih0, dwhh0, db0, dwih1, dwhh1, db1,
                                       linw, linb, outp);
}

// Round 10
// 5058.316 us; speedup vs baseline: 1.0699x; 1.0278x over previous
//
#include <hip/hip_runtime.h>

typedef _Float16 f16;
typedef _Float16 f16x4 __attribute__((ext_vector_type(4)));
typedef _Float16 f16x8 __attribute__((ext_vector_type(8)));
typedef float    f32x4 __attribute__((ext_vector_type(4)));

#define MFMA16(a,b,c) __builtin_amdgcn_mfma_f32_16x16x32_f16((a),(b),(c),0,0,0)

constexpr unsigned NB = 64, NS = 256, NC = 64, NH = 512, NT = 128;
constexpr unsigned HSLOT = NB * NH;                       // f16 elems per h snapshot

// ---- workspace layout (total ~2.70 MB) ----
constexpr unsigned OFF_WX   = 0;                          // x as f16 [64][256][64]  (2 MB)
constexpr unsigned OFF_WLIN = OFF_WX   + NB*NS*NC*2;      // lin_W as f16 [64][512]  (64 KB)
constexpr unsigned OFF_EH0  = OFF_WLIN + NC*NH*2;         // 4 h-rings, 2 slots each (512 KB)
constexpr unsigned OFF_EH1  = OFF_EH0  + 2*HSLOT*2;
constexpr unsigned OFF_DH0  = OFF_EH1  + 2*HSLOT*2;
constexpr unsigned OFF_DH1  = OFF_DH0  + 2*HSLOT*2;
constexpr unsigned OFF_BAR  = OFF_DH1  + 2*HSLOT*2;       // barrier ints (8 KB zeroed)

// h rings: BLOCKED layout, elem(batch b, unit u) at (u/4)*256 + b*4 + (u%4).
// Producer WG writes 64 batches x 8B = 512B contiguous, full lines, no
// cross-WG line sharing (R7: killed the partial-line RMW storm).

// ============================ prep kernel ============================
__global__ void prep_convert(const float* __restrict__ x,
                             const float* __restrict__ linw,
                             char* __restrict__ ws)
{
    unsigned rel = blockIdx.x * 256u + threadIdx.x;
    if (rel < 262144u) {
        float4 v = ((const float4*)x)[rel];
        f16x4 o; o[0]=(f16)v.x; o[1]=(f16)v.y; o[2]=(f16)v.z; o[3]=(f16)v.w;
        ((f16x4*)(ws + OFF_WX))[rel] = o;
    } else if ((rel -= 262144u) < 8192u) {
        float4 v = ((const float4*)linw)[rel];
        f16x4 o; o[0]=(f16)v.x; o[1]=(f16)v.y; o[2]=(f16)v.z; o[3]=(f16)v.w;
        ((f16x4*)(ws + OFF_WLIN))[rel] = o;
    } else if ((rel -= 8192u) < 32768u) {         // zero all 4 h rings (contiguous)
        f16x8 z = {};
        ((f16x8*)(ws + OFF_EH0))[rel] = z;
    } else if ((rel -= 32768u) < 512u) {          // zero barrier block (8 KB)
        int4 z; z.x = z.y = z.z = z.w = 0;
        ((int4*)(ws + OFF_BAR))[rel] = z;
    }
}

// ============================ device helpers ============================

__device__ __forceinline__ float sigm(float v)   { return 1.f / (1.f + __expf(-v)); }
__device__ __forceinline__ float tanh_f(float v) { return 2.f / (1.f + __expf(-2.f * v)) - 1.f; }

// Fine-grained device-coherent h accesses (RELAXED/AGENT = single write-through
// store / cache-bypass load at the coherence point; no bulk L2 maintenance).
__device__ __forceinline__ void h_store8(f16* p, f16x4 v)
{
    union { unsigned long long u; f16x4 h; } c; c.h = v;
    __hip_atomic_store((unsigned long long*)p, c.u, __ATOMIC_RELAXED, __HIP_MEMORY_SCOPE_AGENT);
}
__device__ __forceinline__ f16x4 h_load8(const f16* p)
{
    unsigned long long v = __hip_atomic_load((const unsigned long long*)p,
                                             __ATOMIC_RELAXED, __HIP_MEMORY_SCOPE_AGENT);
    union { unsigned long long u; f16x4 h; } c; c.u = v;
    return c.h;
}
// A[m][kr..kr+7] from a blocked ring slot (kr multiple of 8)
__device__ __forceinline__ f16x8 h_load_blk(const f16* slot, int kr, int m)
{
    const f16* p = slot + ((kr >> 2) << 8) + (m << 2);
    f16x4 a = h_load8(p);
    f16x4 b = h_load8(p + 256);
    f16x8 r;
    r[0]=a[0]; r[1]=a[1]; r[2]=a[2]; r[3]=a[3];
    r[4]=b[0]; r[5]=b[1]; r[6]=b[2]; r[7]=b[3];
    return r;
}

// Barrier: R7-proven topology (16 groups x 16 WGs, root counter, 16
// distributed release-flag lines; 16 pollers per flag line). ALL RELAXED.
// Ordering is structural: leading __syncthreads drains all h stores
// (write-through, ack'd at coherence point) before tid0's arrival issues;
// consumer h loads bypass L2 and read the coherence point directly.
__device__ __forceinline__ void grid_barrier(int* bar, int wg, int tid, int& bgen)
{
    __syncthreads();                           // drain all threads' stores/loads
    if (tid == 0) {
        const int g = wg >> 4;                 // 16 groups of 16 WGs
        int* grp   = bar + g * 32;             // 128B-spaced counters
        int* root  = bar + 16 * 32;
        int* flags = bar + 17 * 32;            // 16 flag words, 128B apart
        const int target = bgen + 1;

        int old = __hip_atomic_fetch_add(grp, 1, __ATOMIC_RELAXED, __HIP_MEMORY_SCOPE_AGENT);
        if ((old & 15) == 15) {                // group complete
            int ro = __hip_atomic_fetch_add(root, 1, __ATOMIC_RELAXED, __HIP_MEMORY_SCOPE_AGENT);
            if ((ro & 15) == 15) {             // all 16 groups complete
                #pragma unroll
                for (int i = 0; i < 16; ++i)
                    __hip_atomic_store(flags + i * 32, target, __ATOMIC_RELAXED, __HIP_MEMORY_SCOPE_AGENT);
            }
        }
        int* myf = flags + g * 32;
        while (__hip_atomic_load(myf, __ATOMIC_RELAXED, __HIP_MEMORY_SCOPE_AGENT) < target)
            __builtin_amdgcn_s_sleep(1);
        bgen = target;
    }
    __syncthreads();
}

// load this WG's 16 weight rows ([A | B] concat along K) fp32 -> f16 LDS
__device__ __forceinline__ void load_wlds_f32(f16 (*Wlds)[1032],
                                              const float* __restrict__ A, int KA,
                                              const float* __restrict__ Bs, int KB,
                                              int u0, int tid)
{
    int nch = (KA + KB) >> 2;       // float4 chunks per row
    int tot = nch << 4;
    for (int idx = tid; idx < tot; idx += 256) {
        int j = idx / nch, ch = idx - j * nch;
        int k = ch << 2;
        int grow = ((j >> 2) << 9) + u0 + (j & 3);   // gate*512 + unit
        float4 v;
        if (k < KA) v = *(const float4*)(A + grow * KA + k);
        else        v = *(const float4*)(Bs + grow * KB + (k - KA));
        f16x4 o; o[0]=(f16)v.x; o[1]=(f16)v.y; o[2]=(f16)v.z; o[3]=(f16)v.w;
        *(f16x4*)&Wlds[j][k] = o;
    }
}

// decoder-L0 weights: rows = [Wfold = dec_Wih0 @ lin_W (512) | dec_Whh0 (512)]
__device__ __forceinline__ void load_wlds_fold(f16 (*Wlds)[1032],
                                               const float* __restrict__ dwih0,
                                               const float* __restrict__ linw,
                                               const float* __restrict__ dwhh0,
                                               int u0, int tid)
{
    {   // fold part: each thread computes 32 consecutive k in one row
        int idx = tid << 5;
        int j = idx >> 9, k0 = idx & 511;
        int grow = ((j >> 2) << 9) + u0 + (j & 3);
        float acc[32];
        #pragma unroll
        for (int q = 0; q < 32; ++q) acc[q] = 0.f;
        for (int c = 0; c < 64; ++c) {
            float wc = dwih0[grow * 64 + c];
            const float* lr = linw + c * 512 + k0;
            #pragma unroll
            for (int q = 0; q < 32; ++q) acc[q] += wc * lr[q];
        }
        #pragma unroll
        for (int q = 0; q < 32; ++q) Wlds[j][k0 + q] = (f16)acc[q];
    }
    int tot = 2048;                 // dwhh0 part: 16 rows x 128 float4
    for (int idx = tid; idx < tot; idx += 256) {
        int j = idx >> 7, ch = idx & 127, k = ch << 2;
        int grow = ((j >> 2) << 9) + u0 + (j & 3);
        float4 v = *(const float4*)(dwhh0 + grow * 512 + k);
        f16x4 o; o[0]=(f16)v.x; o[1]=(f16)v.y; o[2]=(f16)v.z; o[3]=(f16)v.w;
        *(f16x4*)&Wlds[j][512 + k] = o;
    }
}

// one recurrent step for this WG's 4 hidden units.
// Per-wave batch partition (no Dp LDS round-trip, no extra __syncthreads),
// but with FOUR independent accumulator chains: slice s feeds chain
// (s-sBeg)&3, partials summed at the end. R8/R9's single dependent chain
// exposed ~24 extra uncached-load latencies per round (+4.5us/round,
// 2.86->5.2ms); 4 chains restore R7's ILP depth while keeping the shuffle
// epilogue. Thread ownership (batch = 16*wv + (lane>>2), unit = u0+(lane&3))
// fixed across ALL phases -> creg carries encoder->decoder untouched.
__device__ __forceinline__ void rnn_round(f16 (*Wlds)[1032],
                                          const f16* __restrict__ A0, int ld0, int K0,
                                          bool a0_plain,
                                          const f16* __restrict__ A1,
                                          int K, int kStart,
                                          const float* ba, float& creg,
                                          f16* __restrict__ ho,
                                          int u0, int tid)
{
    const int lane = tid & 63, wv = tid >> 6, q = lane >> 4, lo = lane & 15;
    const int wbase = wv << 4;                 // this wave's 16-batch tile
    const int sBeg = kStart >> 5, nEnd = K >> 5;
    f32x4 acc[4];
    acc[0] = f32x4{0.f,0.f,0.f,0.f}; acc[1] = acc[0]; acc[2] = acc[0]; acc[3] = acc[0];
    #pragma unroll 4
    for (int s = sBeg; s < nEnd; ++s) {
        int kk = (s << 5) + (q << 3);
        f16x8 bf = *(const f16x8*)&Wlds[lo][kk];
        f16x8 a;
        if (kk < K0) {                         // uniform per slice (K0 % 32 == 0)
            if (a0_plain) a = *(const f16x8*)(A0 + kk + (wbase + lo) * ld0);
            else          a = h_load_blk(A0, kk, wbase + lo);
        } else {
            a = h_load_blk(A1, kk - K0, wbase + lo);
        }
        int c = (s - sBeg) & 3;
        acc[c] = MFMA16(a, bf, acc[c]);
    }
    f32x4 ac;
    #pragma unroll
    for (int r = 0; r < 4; ++r)
        ac[r] = (acc[0][r] + acc[1][r]) + (acc[2][r] + acc[3][r]);
    // gather the 4 gate columns for this thread's (batch, unit)
    const int rsel  = (lane >> 2) & 3;
    const int sbase = (lane & 48) | (lane & 3);
    float v[4];
    #pragma unroll
    for (int g = 0; g < 4; ++g) {
        int src = sbase | (g << 2);
        float t0 = __shfl(ac[0], src);
        float t1 = __shfl(ac[1], src);
        float t2 = __shfl(ac[2], src);
        float t3 = __shfl(ac[3], src);
        float tv = (rsel == 0) ? t0 : (rsel == 1) ? t1 : (rsel == 2) ? t2 : t3;
        v[g] = tv + ba[g];
    }
    float ii = sigm(v[0]), ff = sigm(v[1]), gg = tanh_f(v[2]), oo = sigm(v[3]);
    creg = ff * creg + ii * gg;
    float h = oo * tanh_f(creg);
    // lanes 4k..4k+3 = same batch, units 0..3 -> pack into one 8B store
    float h1 = __shfl_down(h, 1);
    float h2 = __shfl_down(h, 2);
    float h3 = __shfl_down(h, 3);
    if ((lane & 3) == 0) {
        f16x4 hv; hv[0]=(f16)h; hv[1]=(f16)h1; hv[2]=(f16)h2; hv[3]=(f16)h3;
        int m = wbase + (lane >> 2);
        h_store8(ho + ((u0 >> 2) << 8) + (m << 2), hv);
    }
}

// out_t tile: 16 batches x 64 cols = h1_t @ lin_W^T + lin_b  (H1 blocked).
// Also 4 independent chains (this runs on the even-round critical path).
__device__ __forceinline__ void out_gemm(const f16* __restrict__ H1,
                                         const f16* __restrict__ LW,
                                         const float* __restrict__ linb,
                                         float* __restrict__ out,
                                         int w, int t, int tid)
{
    const int lane = tid & 63, wv = tid >> 6, q = lane >> 4, lo = lane & 15;
    int b0 = w << 4;
    f32x4 acc[4];
    acc[0] = f32x4{0.f,0.f,0.f,0.f}; acc[1] = acc[0]; acc[2] = acc[0]; acc[3] = acc[0];
    int c0 = wv << 4;
    #pragma unroll 4
    for (int s = 0; s < 16; ++s) {
        int kk = (s << 5) + (q << 3);
        f16x8 bf = *(const f16x8*)(LW + (c0 + lo) * 512 + kk);
        f16x8 a  = h_load_blk(H1, kk, b0 + lo);
        acc[s & 3] = MFMA16(a, bf, acc[s & 3]);
    }
    float lb = linb[c0 + lo];
    #pragma unroll
    for (int r = 0; r < 4; ++r) {
        int b = b0 + (q << 2) + r;
        float v = (acc[0][r] + acc[1][r]) + (acc[2][r] + acc[3][r]);
        out[(size_t)b * (NT * NC) + t * NC + c0 + lo] = v + lb;
    }
}

// ============================ main persistent kernel ============================
// Plain (non-cooperative) launch: 256 WGs x 256 thr, ~33 KB LDS/WG -> >=3
// WGs/CU capacity, whole grid co-resident by capacity; hand-rolled device
// barrier cannot deadlock. Cooperative launch is not graph-capture-safe.

__global__ void __launch_bounds__(256)
lstm_main(char* __restrict__ ws,
          const float* __restrict__ x,
          const float* __restrict__ wih0, const float* __restrict__ whh0, const float* __restrict__ eb0,
          const float* __restrict__ wih1, const float* __restrict__ whh1, const float* __restrict__ eb1,
          const float* __restrict__ dwih0, const float* __restrict__ dwhh0, const float* __restrict__ db0,
          const float* __restrict__ dwih1, const float* __restrict__ dwhh1, const float* __restrict__ db1,
          const float* __restrict__ linw, const float* __restrict__ linb,
          float* __restrict__ out)
{
    __shared__ f16 Wlds[16][1032];   // this WG's 16 weight rows (K-padded)

    const int wg = blockIdx.x, tid = threadIdx.x;
    const bool isL0 = wg < 128;
    const int u0 = (wg & 127) << 2;
    const int uu = tid & 3;
    int* bar = (int*)(ws + OFF_BAR);
    int bgen = 0;

    const f16* WX   = (const f16*)(ws + OFF_WX);
    const f16* WLIN = (const f16*)(ws + OFF_WLIN);
    f16* EH0 = (f16*)(ws + OFF_EH0);
    f16* EH1 = (f16*)(ws + OFF_EH1);
    f16* DH0 = (f16*)(ws + OFF_DH0);
    f16* DH1 = (f16*)(ws + OFF_DH1);

    // ---------------- encoder (layer1 pipelined one step behind layer0) ----------------
    if (isL0) load_wlds_f32(Wlds, wih0,  64, whh0, 512, u0, tid);
    else      load_wlds_f32(Wlds, wih1, 512, whh1, 512, u0, tid);
    __syncthreads();

    float ba[4];
    {
        const float* bs = isL0 ? eb0 : eb1;
        #pragma unroll
        for (int g = 0; g < 4; ++g) ba[g] = bs[(g << 9) + u0 + uu];
    }
    float creg = 0.f;   // cell state: fixed (batch,unit) per thread across ALL phases

    for (int r = 0; r <= (int)NS; ++r) {
        if (isL0 && r < (int)NS) {
            rnn_round(Wlds,
                      WX + r * 64, NS * NC, 64, true,
                      EH0 + ((r + 1) & 1) * HSLOT,
                      576, 0, ba, creg,
                      EH0 + (r & 1) * HSLOT, u0, tid);
        } else if (!isL0 && r >= 1) {
            int t = r - 1;
            rnn_round(Wlds,
                      EH0 + (t & 1) * HSLOT, 512, 512, false,
                      EH1 + ((t + 1) & 1) * HSLOT,
                      1024, 0, ba, creg,
                      EH1 + (t & 1) * HSLOT, u0, tid);
        }
        grid_barrier(bar, wg, tid, bgen);
    }

    // ---------------- decoder setup (fold linear into layer0) ----------------
    float baI[4];
    if (isL0) {
        load_wlds_fold(Wlds, dwih0, linw, dwhh0, u0, tid);
        const int m = ((tid >> 6) << 4) | ((tid & 63) >> 2);   // this thread's batch
        const float* xr = x + m * (NS * NC) + (NS - 1) * NC;
        #pragma unroll
        for (int g = 0; g < 4; ++g) {
            int row = (g << 9) + u0 + uu;
            const float* wr = dwih0 + row * 64;
            float bsum = 0.f, xsum = 0.f;
            for (int c = 0; c < 64; ++c) { bsum += linb[c] * wr[c]; xsum += xr[c] * wr[c]; }
            ba[g]  = db0[row] + bsum;   // folded bias (t>=1)
            baI[g] = db0[row] + xsum;   // t==0 bias: x_last @ dec_Wih0^T + dec_b0
        }
    } else {
        load_wlds_f32(Wlds, dwih1, 512, dwhh1, 512, u0, tid);
        #pragma unroll
        for (int g = 0; g < 4; ++g) { ba[g] = db1[(g << 9) + u0 + uu]; baI[g] = 0.f; }
    }
    __syncthreads();

    // ---------------- decoder: 2 rounds/step; idle WGs 128..131 emit out_{t-1} ----------------
    for (int d = 0; d < 2 * (int)NT; ++d) {
        int t = d >> 1;
        if ((d & 1) == 0) {
            if (isL0) {
                const f16* A0 = (t == 0) ? EH1 + HSLOT : DH1 + ((t + 1) & 1) * HSLOT; // h1_{t-1} (Wfold)
                const f16* A1 = (t == 0) ? EH0 + HSLOT : DH0 + ((t + 1) & 1) * HSLOT; // h0_{t-1} (Whh0)
                rnn_round(Wlds, A0, 512, 512, false, A1, 1024, (t == 0) ? 512 : 0,
                          (t == 0) ? baI : ba, creg,
                          DH0 + (t & 1) * HSLOT, u0, tid);
            } else if (wg < 132 && t >= 1) {
                out_gemm(DH1 + ((t - 1) & 1) * HSLOT, WLIN, linb, out, wg - 128, t - 1, tid);
            }
        } else {
            if (!isL0) {
                const f16* A0 = DH0 + (t & 1) * HSLOT;                                 // h0_t (Wih1)
                const f16* A1 = (t == 0) ? EH1 + HSLOT : DH1 + ((t + 1) & 1) * HSLOT;  // h1_{t-1} (Whh1)
                rnn_round(Wlds, A0, 512, 512, false, A1, 1024, 0, ba, creg,
                          DH1 + (t & 1) * HSLOT, u0, tid);
            }
        }
        grid_barrier(bar, wg, tid, bgen);
    }

    // final out_{127} (h1_{127} is in DH1 slot 1; last grid_barrier already synced it)
    if (!isL0 && wg < 132)
        out_gemm(DH1 + HSLOT, WLIN, linb, out, wg - 128, (int)NT - 1, tid);
}

// ============================ host launch ============================

extern "C" void kernel_launch(void* const* d_in, const int* in_sizes, int n_in,
                              void* d_out, int out_size, void* d_ws, size_t ws_size,
                              hipStream_t stream)
{
    // setup_inputs() dict order: x, target_len, enc_Wih0, enc_Whh0, enc_b0,
    // enc_Wih1, enc_Whh1, enc_b1, dec_Wih0, dec_Whh0, dec_b0, dec_Wih1,
    // dec_Whh1, dec_b1, lin_W, lin_b.  (target_len at index 1!)
    const float* x     = (const float*)d_in[0];
    const float* wih0  = (const float*)d_in[2];
    const float* whh0  = (const float*)d_in[3];
    const float* eb0   = (const float*)d_in[4];
    const float* wih1  = (const float*)d_in[5];
    const float* whh1  = (const float*)d_in[6];
    const float* eb1   = (const float*)d_in[7];
    const float* dwih0 = (const float*)d_in[8];
    const float* dwhh0 = (const float*)d_in[9];
    const float* db0   = (const float*)d_in[10];
    const float* dwih1 = (const float*)d_in[11];
    const float* dwhh1 = (const float*)d_in[12];
    const float* db1   = (const float*)d_in[13];
    const float* linw  = (const float*)d_in[14];
    const float* linb  = (const float*)d_in[15];
    char* ws    = (char*)d_ws;
    float* outp = (float*)d_out;

    prep_convert<<<1187, 256, 0, stream>>>(x, linw, ws);

    // plain launch (graph-capture safe); co-residency by capacity, see comment above
    lstm_main<<<256, 256, 0, stream>>>(ws, x, wih0, whh0, eb0, wih1, whh1, eb1,
                                       dwih0, dwhh0, db0, dwih1, dwhh1, db1,
                                       linw, linb, outp);
}

// Round 11
// 2474.540 us; speedup vs baseline: 2.1870x; 2.0441x over previous
//
#include <hip/hip_runtime.h>

typedef _Float16 f16;
typedef _Float16 f16x4 __attribute__((ext_vector_type(4)));
typedef _Float16 f16x8 __attribute__((ext_vector_type(8)));
typedef float    f32x4 __attribute__((ext_vector_type(4)));

#define MFMA16(a,b,c) __builtin_amdgcn_mfma_f32_16x16x32_f16((a),(b),(c),0,0,0)

constexpr unsigned NB = 64, NS = 256, NC = 64, NH = 512, NT = 128;
constexpr unsigned HSLOT = NB * NH;                       // f16 elems per h snapshot

// ---- workspace layout (total ~2.70 MB) ----
constexpr unsigned OFF_WX   = 0;                          // x as f16 [64][256][64]  (2 MB)
constexpr unsigned OFF_WLIN = OFF_WX   + NB*NS*NC*2;      // lin_W as f16 [64][512]  (64 KB)
constexpr unsigned OFF_EH0  = OFF_WLIN + NC*NH*2;         // 4 h-rings, 2 slots each (512 KB)
constexpr unsigned OFF_EH1  = OFF_EH0  + 2*HSLOT*2;
constexpr unsigned OFF_DH0  = OFF_EH1  + 2*HSLOT*2;
constexpr unsigned OFF_DH1  = OFF_DH0  + 2*HSLOT*2;
constexpr unsigned OFF_BAR  = OFF_DH1  + 2*HSLOT*2;       // barrier ints (8 KB zeroed)

// h rings: BLOCKED layout, elem(batch b, unit u) at (u/4)*256 + b*4 + (u%4).
// Producer WG writes 64 batches x 8B = 512B contiguous, full lines, no
// cross-WG line sharing (R7: killed the partial-line RMW storm).
//
// GEMM partition: R7-proven split-K (wave w takes K/4 slices, all 64 batches,
// 4 m-tile fragments per iteration = 8 independent loads in flight per
// exposed wait) + Dp LDS cross-wave reduce. R8-R10's per-wave full-K variant
// (2 loads per branchy iteration) exposed ~32 serial uncached-load waits
// -> +4us/round regression; chain-count (R10) did NOT fix it, load batching
// is the controlling variable.

// ============================ prep kernel ============================
__global__ void prep_convert(const float* __restrict__ x,
                             const float* __restrict__ linw,
                             char* __restrict__ ws)
{
    unsigned rel = blockIdx.x * 256u + threadIdx.x;
    if (rel < 262144u) {
        float4 v = ((const float4*)x)[rel];
        f16x4 o; o[0]=(f16)v.x; o[1]=(f16)v.y; o[2]=(f16)v.z; o[3]=(f16)v.w;
        ((f16x4*)(ws + OFF_WX))[rel] = o;
    } else if ((rel -= 262144u) < 8192u) {
        float4 v = ((const float4*)linw)[rel];
        f16x4 o; o[0]=(f16)v.x; o[1]=(f16)v.y; o[2]=(f16)v.z; o[3]=(f16)v.w;
        ((f16x4*)(ws + OFF_WLIN))[rel] = o;
    } else if ((rel -= 8192u) < 32768u) {         // zero all 4 h rings (contiguous)
        f16x8 z = {};
        ((f16x8*)(ws + OFF_EH0))[rel] = z;
    } else if ((rel -= 32768u) < 512u) {          // zero barrier block (8 KB)
        int4 z; z.x = z.y = z.z = z.w = 0;
        ((int4*)(ws + OFF_BAR))[rel] = z;
    }
}

// ============================ device helpers ============================

__device__ __forceinline__ float sigm(float v)   { return 1.f / (1.f + __expf(-v)); }
__device__ __forceinline__ float tanh_f(float v) { return 2.f / (1.f + __expf(-2.f * v)) - 1.f; }

// Fine-grained device-coherent h accesses (RELAXED/AGENT = single write-through
// store / cache-bypass load at the coherence point; no bulk L2 maintenance).
__device__ __forceinline__ void h_store8(f16* p, f16x4 v)
{
    union { unsigned long long u; f16x4 h; } c; c.h = v;
    __hip_atomic_store((unsigned long long*)p, c.u, __ATOMIC_RELAXED, __HIP_MEMORY_SCOPE_AGENT);
}
__device__ __forceinline__ f16x4 h_load8(const f16* p)
{
    unsigned long long v = __hip_atomic_load((const unsigned long long*)p,
                                             __ATOMIC_RELAXED, __HIP_MEMORY_SCOPE_AGENT);
    union { unsigned long long u; f16x4 h; } c; c.u = v;
    return c.h;
}
// A[m][kr..kr+7] from a blocked ring slot (kr multiple of 8)
__device__ __forceinline__ f16x8 h_load_blk(const f16* slot, int kr, int m)
{
    const f16* p = slot + ((kr >> 2) << 8) + (m << 2);
    f16x4 a = h_load8(p);
    f16x4 b = h_load8(p + 256);
    f16x8 r;
    r[0]=a[0]; r[1]=a[1]; r[2]=a[2]; r[3]=a[3];
    r[4]=b[0]; r[5]=b[1]; r[6]=b[2]; r[7]=b[3];
    return r;
}

// Barrier: R7-proven topology (16 groups x 16 WGs, root counter, 16
// distributed release-flag lines; 16 pollers per flag line). ALL RELAXED.
// Ordering is structural: leading __syncthreads drains all h stores
// (write-through, ack'd at coherence point) before tid0's arrival issues;
// consumer h loads bypass L2 and read the coherence point directly.
__device__ __forceinline__ void grid_barrier(int* bar, int wg, int tid, int& bgen)
{
    __syncthreads();                           // drain all threads' stores/loads
    if (tid == 0) {
        const int g = wg >> 4;                 // 16 groups of 16 WGs
        int* grp   = bar + g * 32;             // 128B-spaced counters
        int* root  = bar + 16 * 32;
        int* flags = bar + 17 * 32;            // 16 flag words, 128B apart
        const int target = bgen + 1;

        int old = __hip_atomic_fetch_add(grp, 1, __ATOMIC_RELAXED, __HIP_MEMORY_SCOPE_AGENT);
        if ((old & 15) == 15) {                // group complete
            int ro = __hip_atomic_fetch_add(root, 1, __ATOMIC_RELAXED, __HIP_MEMORY_SCOPE_AGENT);
            if ((ro & 15) == 15) {             // all 16 groups complete
                #pragma unroll
                for (int i = 0; i < 16; ++i)
                    __hip_atomic_store(flags + i * 32, target, __ATOMIC_RELAXED, __HIP_MEMORY_SCOPE_AGENT);
            }
        }
        int* myf = flags + g * 32;
        while (__hip_atomic_load(myf, __ATOMIC_RELAXED, __HIP_MEMORY_SCOPE_AGENT) < target)
            __builtin_amdgcn_s_sleep(1);
        bgen = target;
    }
    __syncthreads();
}

// load this WG's 16 weight rows ([A | B] concat along K) fp32 -> f16 LDS
__device__ __forceinline__ void load_wlds_f32(f16 (*Wlds)[1032],
                                              const float* __restrict__ A, int KA,
                                              const float* __restrict__ Bs, int KB,
                                              int u0, int tid)
{
    int nch = (KA + KB) >> 2;       // float4 chunks per row
    int tot = nch << 4;
    for (int idx = tid; idx < tot; idx += 256) {
        int j = idx / nch, ch = idx - j * nch;
        int k = ch << 2;
        int grow = ((j >> 2) << 9) + u0 + (j & 3);   // gate*512 + unit
        float4 v;
        if (k < KA) v = *(const float4*)(A + grow * KA + k);
        else        v = *(const float4*)(Bs + grow * KB + (k - KA));
        f16x4 o; o[0]=(f16)v.x; o[1]=(f16)v.y; o[2]=(f16)v.z; o[3]=(f16)v.w;
        *(f16x4*)&Wlds[j][k] = o;
    }
}

// decoder-L0 weights: rows = [Wfold = dec_Wih0 @ lin_W (512) | dec_Whh0 (512)]
__device__ __forceinline__ void load_wlds_fold(f16 (*Wlds)[1032],
                                               const float* __restrict__ dwih0,
                                               const float* __restrict__ linw,
                                               const float* __restrict__ dwhh0,
                                               int u0, int tid)
{
    {   // fold part: each thread computes 32 consecutive k in one row
        int idx = tid << 5;
        int j = idx >> 9, k0 = idx & 511;
        int grow = ((j >> 2) << 9) + u0 + (j & 3);
        float acc[32];
        #pragma unroll
        for (int q = 0; q < 32; ++q) acc[q] = 0.f;
        for (int c = 0; c < 64; ++c) {
            float wc = dwih0[grow * 64 + c];
            const float* lr = linw + c * 512 + k0;
            #pragma unroll
            for (int q = 0; q < 32; ++q) acc[q] += wc * lr[q];
        }
        #pragma unroll
        for (int q = 0; q < 32; ++q) Wlds[j][k0 + q] = (f16)acc[q];
    }
    int tot = 2048;                 // dwhh0 part: 16 rows x 128 float4
    for (int idx = tid; idx < tot; idx += 256) {
        int j = idx >> 7, ch = idx & 127, k = ch << 2;
        int grow = ((j >> 2) << 9) + u0 + (j & 3);
        float4 v = *(const float4*)(dwhh0 + grow * 512 + k);
        f16x4 o; o[0]=(f16)v.x; o[1]=(f16)v.y; o[2]=(f16)v.z; o[3]=(f16)v.w;
        *(f16x4*)&Wlds[j][512 + k] = o;
    }
}

// one recurrent step for this WG's 4 hidden units (R7 structure).
// Split-K: wave w covers slices [s0, s0+ns) for ALL 64 batches (4 m-tile
// fragments per slice = 8 independent loads per iteration). NEW vs R7:
// depth-1 software prefetch — slice s+1's fragments are loaded into nxt[]
// BEFORE the MFMAs on cur[], so the compiler can wait with vmcnt(8) instead
// of vmcnt(0) and each iteration's load latency overlaps 4 MFMAs.
__device__ __forceinline__ void rnn_round(f16 (*Wlds)[1032], float (*Dp)[64][17],
                                          const f16* __restrict__ A0, int ld0, int K0,
                                          bool a0_plain,
                                          const f16* __restrict__ A1,
                                          int K, int kStart,
                                          const float* ba, float& creg,
                                          f16* __restrict__ ho,
                                          int u0, int tid)
{
    const int lane = tid & 63, wv = tid >> 6, q = lane >> 4, lo = lane & 15;
    int sBeg = kStart >> 5, n = (K >> 5) - sBeg;
    int per = n >> 2, rem = n & 3;
    int s0 = sBeg + wv * per + (wv < rem ? wv : rem);
    int ns = per + (wv < rem ? 1 : 0);
    f32x4 ac0 = {0.f,0.f,0.f,0.f}, ac1 = ac0, ac2 = ac0, ac3 = ac0;

    auto load4 = [&](int s, f16x8* A) {
        int kk = (s << 5) + (q << 3);
        if (kk < K0 && a0_plain) {
            const f16* p0 = A0 + kk + lo * ld0;
            A[0] = *(const f16x8*)(p0);
            A[1] = *(const f16x8*)(p0 + 16 * ld0);
            A[2] = *(const f16x8*)(p0 + 32 * ld0);
            A[3] = *(const f16x8*)(p0 + 48 * ld0);
        } else if (kk < K0) {
            A[0] = h_load_blk(A0, kk, lo);
            A[1] = h_load_blk(A0, kk, lo + 16);
            A[2] = h_load_blk(A0, kk, lo + 32);
            A[3] = h_load_blk(A0, kk, lo + 48);
        } else {
            int kr = kk - K0;
            A[0] = h_load_blk(A1, kr, lo);
            A[1] = h_load_blk(A1, kr, lo + 16);
            A[2] = h_load_blk(A1, kr, lo + 32);
            A[3] = h_load_blk(A1, kr, lo + 48);
        }
    };

    f16x8 cur[4], nxt[4];
    if (ns > 0) load4(s0, cur);
    for (int s = s0; s < s0 + ns; ++s) {
        if (s + 1 < s0 + ns) load4(s + 1, nxt);   // prefetch before use of cur
        int kk = (s << 5) + (q << 3);
        f16x8 bf = *(const f16x8*)&Wlds[lo][kk];
        ac0 = MFMA16(cur[0], bf, ac0);
        ac1 = MFMA16(cur[1], bf, ac1);
        ac2 = MFMA16(cur[2], bf, ac2);
        ac3 = MFMA16(cur[3], bf, ac3);
        cur[0] = nxt[0]; cur[1] = nxt[1]; cur[2] = nxt[2]; cur[3] = nxt[3];
    }
    #pragma unroll
    for (int r = 0; r < 4; ++r) {
        int rr = (q << 2) + r;
        Dp[wv][rr     ][lo] = ac0[r];
        Dp[wv][rr + 16][lo] = ac1[r];
        Dp[wv][rr + 32][lo] = ac2[r];
        Dp[wv][rr + 48][lo] = ac3[r];
    }
    __syncthreads();
    const int m = tid >> 2, uu = tid & 3;
    float v[4];
    #pragma unroll
    for (int g = 0; g < 4; ++g) {
        int col = (g << 2) + uu;
        v[g] = Dp[0][m][col] + Dp[1][m][col] + Dp[2][m][col] + Dp[3][m][col] + ba[g];
    }
    float ii = sigm(v[0]), ff = sigm(v[1]), gg = tanh_f(v[2]), oo = sigm(v[3]);
    creg = ff * creg + ii * gg;
    float h = oo * tanh_f(creg);
    // pack the 4 gate-threads' h into one aligned 8B word; blocked layout:
    // this WG's block (u0/4) at +m*4 -> 64 batches x 8B = 512B contiguous.
    float h1 = __shfl_down(h, 1);
    float h2 = __shfl_down(h, 2);
    float h3 = __shfl_down(h, 3);
    if (uu == 0) {
        f16x4 hv; hv[0] = (f16)h; hv[1] = (f16)h1; hv[2] = (f16)h2; hv[3] = (f16)h3;
        h_store8(ho + ((u0 >> 2) << 8) + (m << 2), hv);
    }
}

// out_t tile: 16 batches x 64 cols = h1_t @ lin_W^T + lin_b  (H1 blocked)
__device__ __forceinline__ void out_gemm(const f16* __restrict__ H1,
                                         const f16* __restrict__ LW,
                                         const float* __restrict__ linb,
                                         float* __restrict__ out,
                                         int w, int t, int tid)
{
    const int lane = tid & 63, wv = tid >> 6, q = lane >> 4, lo = lane & 15;
    int b0 = w << 4;
    f32x4 ac = {0.f,0.f,0.f,0.f};
    int c0 = wv << 4;
    #pragma unroll 4
    for (int s = 0; s < 16; ++s) {
        int kk = (s << 5) + (q << 3);
        f16x8 bf = *(const f16x8*)(LW + (c0 + lo) * 512 + kk);
        f16x8 a  = h_load_blk(H1, kk, b0 + lo);
        ac = MFMA16(a, bf, ac);
    }
    float lb = linb[c0 + lo];
    #pragma unroll
    for (int r = 0; r < 4; ++r) {
        int b = b0 + (q << 2) + r;
        out[(size_t)b * (NT * NC) + t * NC + c0 + lo] = ac[r] + lb;
    }
}

// ============================ main persistent kernel ============================
// Plain (non-cooperative) launch: 256 WGs x 256 thr, 50.4 KB LDS/WG -> 3 WGs/CU
// capacity (768 slots >= 256 WGs), so the whole grid is co-resident by capacity
// and the hand-rolled device-scope barrier cannot deadlock. Cooperative launch
// is NOT used because it is not graph-capture-safe.

__global__ void __launch_bounds__(256)
lstm_main(char* __restrict__ ws,
          const float* __restrict__ x,
          const float* __restrict__ wih0, const float* __restrict__ whh0, const float* __restrict__ eb0,
          const float* __restrict__ wih1, const float* __restrict__ whh1, const float* __restrict__ eb1,
          const float* __restrict__ dwih0, const float* __restrict__ dwhh0, const float* __restrict__ db0,
          const float* __restrict__ dwih1, const float* __restrict__ dwhh1, const float* __restrict__ db1,
          const float* __restrict__ linw, const float* __restrict__ linb,
          float* __restrict__ out)
{
    __shared__ f16   Wlds[16][1032];   // this WG's 16 weight rows (K-padded)
    __shared__ float Dp[4][64][17];    // per-wave partial gate sums

    const int wg = blockIdx.x, tid = threadIdx.x;
    const bool isL0 = wg < 128;
    const int u0 = (wg & 127) << 2;
    const int uu = tid & 3;
    int* bar = (int*)(ws + OFF_BAR);
    int bgen = 0;

    const f16* WX   = (const f16*)(ws + OFF_WX);
    const f16* WLIN = (const f16*)(ws + OFF_WLIN);
    f16* EH0 = (f16*)(ws + OFF_EH0);
    f16* EH1 = (f16*)(ws + OFF_EH1);
    f16* DH0 = (f16*)(ws + OFF_DH0);
    f16* DH1 = (f16*)(ws + OFF_DH1);

    // ---------------- encoder (layer1 pipelined one step behind layer0) ----------------
    if (isL0) load_wlds_f32(Wlds, wih0,  64, whh0, 512, u0, tid);
    else      load_wlds_f32(Wlds, wih1, 512, whh1, 512, u0, tid);
    __syncthreads();

    float ba[4];
    {
        const float* bs = isL0 ? eb0 : eb1;
        #pragma unroll
        for (int g = 0; g < 4; ++g) ba[g] = bs[(g << 9) + u0 + uu];
    }
    float creg = 0.f;   // cell state: fixed (m,unit) per thread across ALL phases

    for (int r = 0; r <= (int)NS; ++r) {
        if (isL0 && r < (int)NS) {
            rnn_round(Wlds, Dp,
                      WX + r * 64, NS * NC, 64, true,
                      EH0 + ((r + 1) & 1) * HSLOT,
                      576, 0, ba, creg,
                      EH0 + (r & 1) * HSLOT, u0, tid);
        } else if (!isL0 && r >= 1) {
            int t = r - 1;
            rnn_round(Wlds, Dp,
                      EH0 + (t & 1) * HSLOT, 512, 512, false,
                      EH1 + ((t + 1) & 1) * HSLOT,
                      1024, 0, ba, creg,
                      EH1 + (t & 1) * HSLOT, u0, tid);
        }
        grid_barrier(bar, wg, tid, bgen);
    }

    // ---------------- decoder setup (fold linear into layer0) ----------------
    float baI[4];
    if (isL0) {
        load_wlds_fold(Wlds, dwih0, linw, dwhh0, u0, tid);
        const int m = tid >> 2;
        const float* xr = x + m * (NS * NC) + (NS - 1) * NC;
        #pragma unroll
        for (int g = 0; g < 4; ++g) {
            int row = (g << 9) + u0 + uu;
            const float* wr = dwih0 + row * 64;
            float bsum = 0.f, xsum = 0.f;
            for (int c = 0; c < 64; ++c) { bsum += linb[c] * wr[c]; xsum += xr[c] * wr[c]; }
            ba[g]  = db0[row] + bsum;   // folded bias (t>=1)
            baI[g] = db0[row] + xsum;   // t==0 bias: x_last @ dec_Wih0^T + dec_b0
        }
    } else {
        load_wlds_f32(Wlds, dwih1, 512, dwhh1, 512, u0, tid);
        #pragma unroll
        for (int g = 0; g < 4; ++g) { ba[g] = db1[(g << 9) + u0 + uu]; baI[g] = 0.f; }
    }
    __syncthreads();

    // ---------------- decoder: 2 rounds/step; idle WGs 128..131 emit out_{t-1} ----------------
    for (int d = 0; d < 2 * (int)NT; ++d) {
        int t = d >> 1;
        if ((d & 1) == 0) {
            if (isL0) {
                const f16* A0 = (t == 0) ? EH1 + HSLOT : DH1 + ((t + 1) & 1) * HSLOT; // h1_{t-1} (Wfold)
                const f16* A1 = (t == 0) ? EH0 + HSLOT : DH0 + ((t + 1) & 1) * HSLOT; // h0_{t-1} (Whh0)
                rnn_round(Wlds, Dp, A0, 512, 512, false, A1, 1024, (t == 0) ? 512 : 0,
                          (t == 0) ? baI : ba, creg,
                          DH0 + (t & 1) * HSLOT, u0, tid);
            } else if (wg < 132 && t >= 1) {
                out_gemm(DH1 + ((t - 1) & 1) * HSLOT, WLIN, linb, out, wg - 128, t - 1, tid);
            }
        } else {
            if (!isL0) {
                const f16* A0 = DH0 + (t & 1) * HSLOT;                                 // h0_t (Wih1)
                const f16* A1 = (t == 0) ? EH1 + HSLOT : DH1 + ((t + 1) & 1) * HSLOT;  // h1_{t-1} (Whh1)
                rnn_round(Wlds, Dp, A0, 512, 512, false, A1, 1024, 0, ba, creg,
                          DH1 + (t & 1) * HSLOT, u0, tid);
            }
        }
        grid_barrier(bar, wg, tid, bgen);
    }

    // final out_{127} (h1_{127} is in DH1 slot 1; last grid_barrier already synced it)
    if (!isL0 && wg < 132)
        out_gemm(DH1 + HSLOT, WLIN, linb, out, wg - 128, (int)NT - 1, tid);
}

// ============================ host launch ============================

extern "C" void kernel_launch(void* const* d_in, const int* in_sizes, int n_in,
                              void* d_out, int out_size, void* d_ws, size_t ws_size,
                              hipStream_t stream)
{
    // setup_inputs() dict order: x, target_len, enc_Wih0, enc_Whh0, enc_b0,
    // enc_Wih1, enc_Whh1, enc_b1, dec_Wih0, dec_Whh0, dec_b0, dec_Wih1,
    // dec_Whh1, dec_b1, lin_W, lin_b.  (target_len at index 1!)
    const float* x     = (const float*)d_in[0];
    const float* wih0  = (const float*)d_in[2];
    const float* whh0  = (const float*)d_in[3];
    const float* eb0   = (const float*)d_in[4];
    const float* wih1  = (const float*)d_in[5];
    const float* whh1  = (const float*)d_in[6];
    const float* eb1   = (const float*)d_in[7];
    const float* dwih0 = (const float*)d_in[8];
    const float* dwhh0 = (const float*)d_in[9];
    const float* db0   = (const float*)d_in[10];
    const float* dwih1 = (const float*)d_in[11];
    const float* dwhh1 = (const float*)d_in[12];
    const float* db1   = (const float*)d_in[13];
    const float* linw  = (const float*)d_in[14];
    const float* linb  = (const float*)d_in[15];
    char* ws    = (char*)d_ws;
    float* outp = (float*)d_out;

    prep_convert<<<1187, 256, 0, stream>>>(x, linw, ws);

    // plain launch (graph-capture safe); co-residency by capacity, see comment above
    lstm_main<<<256, 256, 0, stream>>>(ws, x, wih0, whh0, eb0, wih1, whh1, eb1,
                                       dwih0, dwhh0, db0, dwih1, dwhh1, db1,
                                       linw, linb, outp);
}